// Round 12
// baseline (166.390 us; speedup 1.0000x reference)
//
#include <hip/hip_runtime.h>
#include <stdint.h>

typedef short s16x8 __attribute__((ext_vector_type(8)));
typedef __bf16 bf16x8 __attribute__((ext_vector_type(8)));
typedef float f32x4 __attribute__((ext_vector_type(4)));

#define NB 8
#define DIM 512
#define DIMO 512
#define DEMB 512
#define NKER 4
#define HH 64
#define WW 64
#define HP 66
#define WP 72
#define KTOT 4608   // 9 * 512
#define NIT 36      // 72 K-steps of 64, 2 per iteration

__device__ __forceinline__ unsigned short f2bf(float f) {
  unsigned int u = __builtin_bit_cast(unsigned int, f);
  u += 0x7fffu + ((u >> 16) & 1u);
  return (unsigned short)(u >> 16);
}

// ------- kernel 1: embed GEMVs: mod (xc=0..7) + sel softmax (xc=8); 72 blocks -------
__global__ void prep_embed(const float* __restrict__ embed,
                           const float* __restrict__ mod_w,
                           const float* __restrict__ mod_b,
                           const float* __restrict__ adapt_w,
                           const float* __restrict__ adapt_b,
                           float* __restrict__ mod, float* __restrict__ sel) {
  const int bid = blockIdx.x;
  const int b = bid / 9;
  const int xc = bid - b * 9;
  const int t = threadIdx.x;
  const int lane = t & 63, wv = t >> 6;
  const float* e = embed + (size_t)b * DEMB;

  if (xc == 8) {   // sel softmax: wave 0 only
    if (wv == 0) {
      float lg[NKER];
#pragma unroll
      for (int n = 0; n < NKER; ++n) {
        const float* ar = adapt_w + (size_t)n * DEMB;
        float s = 0.f;
#pragma unroll
        for (int k = 0; k < 8; ++k) s += e[lane + 64 * k] * ar[lane + 64 * k];
#pragma unroll
        for (int off = 32; off; off >>= 1) s += __shfl_xor(s, off);
        lg[n] = s + adapt_b[n];
      }
      if (lane == 0) {
        float m = lg[0];
#pragma unroll
        for (int n = 1; n < NKER; ++n) m = fmaxf(m, lg[n]);
        float ex[NKER], sum = 0.f;
#pragma unroll
        for (int n = 0; n < NKER; ++n) { ex[n] = expf(lg[n] - m); sum += ex[n]; }
#pragma unroll
        for (int n = 0; n < NKER; ++n) sel[b * NKER + n] = ex[n] / sum;
      }
    }
    return;
  }

  float ev[8];
#pragma unroll
  for (int k = 0; k < 8; ++k) ev[k] = e[lane + 64 * k];
  const int i0 = xc * 64 + wv * 16;
  for (int r = 0; r < 16; ++r) {
    const float* wr = mod_w + (size_t)(i0 + r) * DEMB;
    float s = 0.f;
#pragma unroll
    for (int k = 0; k < 8; ++k) s += ev[k] * wr[lane + 64 * k];
#pragma unroll
    for (int off = 32; off; off >>= 1) s += __shfl_xor(s, off);
    if (lane == 0) mod[b * DIM + i0 + r] = s + mod_b[i0 + r];
  }
}

// ------- kernel 2: interleaved prep: weight-mix (even bid<1024) + fmap (odd / >=1024) ---
// Weight-mix: sequential per-bank staging into 18.5KB static LDS (coalesced), register
// hoist wreg[4][2][9], then pure-VALU b-loop. Small LDS -> ~8 blocks/CU, so the
// HBM-bound fmap blocks overlap the VALU-bound weight blocks (round-9 failure was the
// 73.7KB dynamic LDS charged to all blocks; round-10's was uncoalesced 36B-stride reads).
__global__ void prep_wf(const float* __restrict__ wbank,
                        const float* __restrict__ sel,
                        const float* __restrict__ mod,
                        const float* __restrict__ fmap,
                        unsigned short* __restrict__ wts,
                        unsigned short* __restrict__ xt) {
  const int bid = blockIdx.x;
  const int t = threadIdx.x;
  const bool is_fmap = (bid >= 1024) || (bid & 1);

  __shared__ float ls[KTOT];         // 18432 B (one bank slice)
  __shared__ float red[8];           // parity-alternating reduction slots

  if (is_fmap) {
    // ---- fmap part ----
    const int f = (bid < 1024) ? (bid >> 1) : (bid - 512);
    const int b = f / 66;
    const int yp = f - b * 66;
    unsigned short* rowb = xt + (((size_t)(b * HP + yp)) * WP) * DIM;
    uint4 z; z.x = 0; z.y = 0; z.z = 0; z.w = 0;

    if (yp == 0 || yp == HP - 1) {         // full-row zero
      uint4* p = (uint4*)rowb;
#pragma unroll
      for (int r = 0; r < 18; ++r) p[t + r * 256] = z;
      return;
    }
#pragma unroll
    for (int r = 0; r < 2; ++r) {          // x-halo zero
      int idx = t + r * 256;
      int pxi = idx >> 6;
      int px = pxi ? (64 + pxi) : 0;
      ((uint4*)(rowb + (size_t)px * DIM))[idx & 63] = z;
    }
    const int x = t & 63;
    const int ic0 = (t >> 6) * 8;
    const float* fb = fmap + (size_t)b * DIM * (HH * WW) + (size_t)(yp - 1) * WW + x;
    unsigned short* ob = rowb + (size_t)(x + 1) * DIM;
    for (int r = 0; r < 16; ++r) {
      int i0 = ic0 + r * 32;
      s16x8 vv;
#pragma unroll
      for (int j = 0; j < 8; ++j)
        vv[j] = (short)f2bf(fb[(size_t)(i0 + j) * (HH * WW)]);
      *(s16x8*)&ob[i0] = vv;
    }
    return;
  }

  // ---- weight-mix part: o = bid>>1 ----
  const int o = bid >> 1;
  float wreg[NKER][2][9];
  for (int n = 0; n < NKER; ++n) {
    const float* wb = wbank + ((size_t)n * DIMO + o) * (DIM * 9);
#pragma unroll
    for (int r = 0; r < 18; ++r)
      ls[t + r * 256] = wb[t + r * 256];   // coalesced global read, linear LDS write
    __syncthreads();
    // hoist: src = (t + p*256)*9 + g ; stride-9 -> 2-way bank conflict (free)
#pragma unroll
    for (int p = 0; p < 2; ++p)
#pragma unroll
      for (int g = 0; g < 9; ++g)
        wreg[n][p][g] = ls[(t + p * 256) * 9 + g];
    __syncthreads();                       // before next bank overwrites ls
  }

  const int lane = t & 63, wv = t >> 6;
  for (int b = 0; b < NB; ++b) {
    const float s0 = sel[b * NKER + 0], s1 = sel[b * NKER + 1];
    const float s2 = sel[b * NKER + 2], s3 = sel[b * NKER + 3];
    const float m0 = mod[b * DIM + t] + 1.0f;
    const float m1 = mod[b * DIM + t + 256] + 1.0f;
    const int par = (b & 1) << 2;

    float vv[18];
    float ss = 0.f;
#pragma unroll
    for (int r = 0; r < 18; ++r) {
      const int p = r & 1, g = r >> 1;
      float w = s0 * wreg[0][p][g] + s1 * wreg[1][p][g]
              + s2 * wreg[2][p][g] + s3 * wreg[3][p][g];
      w *= (p ? m1 : m0);
      vv[r] = w;
      ss += w * w;
    }
    for (int off = 32; off > 0; off >>= 1) ss += __shfl_down(ss, off);
    if (lane == 0) red[wv + par] = ss;
    __syncthreads();
    float tot = red[0 + par] + red[1 + par] + red[2 + par] + red[3 + par];
    float inv = rsqrtf(fmaxf(tot, 1e-8f));
    unsigned short* wo = wts + ((size_t)(b * DIMO + o)) * KTOT;
#pragma unroll
    for (int r = 0; r < 18; ++r)
      wo[t + r * 256] = f2bf(vv[r] * inv);
    // no trailing sync: next b writes the other red[] parity
  }
}

// ---------------- kernel 3: implicit-GEMM conv, 256x256 tile, 8-phase schedule ----------------
// Per batch: C[512 o][4096 p] = A[512][4608] . B[4096][4608]^T (both K-contiguous).
// BM=BN=256, BK=64, 8 waves (2M x 4N), per-wave 128x64. LDS 128KB: 2 dbuf x (A 32KB + B 32KB).
// XCD-chunked block swizzle: XCD i owns batch i. Proven round-3/6/8 schedule (123.3us,
// MfmaUtil 55%, 0 bank conflicts) - UNCHANGED.
__global__ __launch_bounds__(512, 2) void conv_gemm(
    const unsigned short* __restrict__ wts,  // [8][512][4608] bf16
    const unsigned short* __restrict__ xt,   // [8][66][72][512] bf16
    float* __restrict__ out) {               // [8][512][64][64] f32
  extern __shared__ __attribute__((aligned(16))) char smem[];

  const int tid = threadIdx.x;
  const int w = tid >> 6, l = tid & 63;
  const int bid0 = blockIdx.x;
  const int bid = ((bid0 & 7) << 5) | (bid0 >> 3);   // T1: 8 XCDs x 32 blocks, bijective
  const int b = bid >> 5;
  const int mt = (bid >> 4) & 1;
  const int nt = bid & 15;
  const int orow0 = mt << 8;
  const int prow0 = nt << 8;
  const int y0 = nt << 2;                  // 4 image rows per 256-pixel tile
  const int wm = w >> 2, wn = w & 3;       // 2 x 4 wave grid
  const int lr = l & 15, lk = l >> 4;

  const unsigned short* a_base = wts + (size_t)(b * 512 + orow0) * KTOT;
  const unsigned short* x_base = xt + (size_t)b * (HP * WP * DIM);

  const int srow = (w << 3) + (l >> 3);                 // row within 64-row issue
  const int sx8 = (((l & 7) ^ ((l >> 3) & 7)) << 3);    // source chunk (elements), involution
  const int sw0 = ((lk ^ (l & 7)) << 4);                // frag-read byte offset, s=0 (s=1: ^64)
  const int aRow = (((wm << 6) + lr) << 7);
  const int bRow = (((wn << 5) + lr) << 7);

  // per-lane iteration-invariant pixel bases for stageB: (h,j) in {0,1}^2
  int pb[2][2];
#pragma unroll
  for (int h = 0; h < 2; ++h)
#pragma unroll
    for (int j = 0; j < 2; ++j) {
      const int pl = (h << 7) + (j << 6) + srow;
      pb[h][j] = (((y0 + (pl >> 6)) * WP + (pl & 63)) << 9);
    }

  f32x4 acc[2][2][4][2] = {};
  s16x8 aF[2][4], bF0[2][2], bF1[2][2];

  auto stageA = [&](int d, int h, int ks) {
#pragma unroll
    for (int j = 0; j < 2; ++j) {
      const unsigned short* gp = a_base + (size_t)((h << 7) + (j << 6) + srow) * KTOT
                               + (ks << 6) + sx8;
      __builtin_amdgcn_global_load_lds(
          (const __attribute__((address_space(1))) void*)gp,
          (__attribute__((address_space(3))) void*)(smem + (d << 16) + (h << 14) + (j << 13) + (w << 10)),
          16, 0, 0);
    }
  };
  auto stageB = [&](int d, int h, int ks) {
    // uniform k-offset: kykx = ks>>3, ky = kykx/3 via (t*11)>>5 (exact for t in 0..8)
    const int t9 = ks >> 3;
    const int ky = (t9 * 11) >> 5;
    const int koff = ky * (WP << 9) + (t9 - 3 * ky) * 512 + ((ks & 7) << 6);
#pragma unroll
    for (int j = 0; j < 2; ++j) {
      const unsigned short* gp = x_base + pb[h][j] + koff + sx8;
      __builtin_amdgcn_global_load_lds(
          (const __attribute__((address_space(1))) void*)gp,
          (__attribute__((address_space(3))) void*)(smem + (d << 16) + 32768 + (h << 14) + (j << 13) + (w << 10)),
          16, 0, 0);
    }
  };

#define VM4 asm volatile("s_waitcnt vmcnt(4)" ::: "memory")
#define VM2 asm volatile("s_waitcnt vmcnt(2)" ::: "memory")
#define VM0 asm volatile("s_waitcnt vmcnt(0)" ::: "memory")
#define FENCE asm volatile("" ::: "memory")
#define BAR do { FENCE; __builtin_amdgcn_s_barrier(); FENCE; } while (0)

#define LOAD_A(d, mq) \
  _Pragma("unroll") for (int s = 0; s < 2; ++s) \
  _Pragma("unroll") for (int mi = 0; mi < 4; ++mi) \
    aF[s][mi] = *(const s16x8*)(smem + ((d) << 16) + ((mq) << 14) + aRow + (mi << 11) + (sw0 ^ (s << 6)));

#define LOAD_B(d, nq, BF) \
  _Pragma("unroll") for (int s = 0; s < 2; ++s) \
  _Pragma("unroll") for (int nj = 0; nj < 2; ++nj) \
    BF[s][nj] = *(const s16x8*)(smem + ((d) << 16) + 32768 + ((nq) << 14) + bRow + (nj << 11) + (sw0 ^ (s << 6)));

#define MFMA_Q(mq, nq, BF) do { \
  __builtin_amdgcn_s_setprio(1); \
  _Pragma("unroll") for (int s = 0; s < 2; ++s) \
  _Pragma("unroll") for (int mi = 0; mi < 4; ++mi) \
  _Pragma("unroll") for (int nj = 0; nj < 2; ++nj) \
    acc[mq][nq][mi][nj] = __builtin_amdgcn_mfma_f32_16x16x32_bf16( \
        __builtin_bit_cast(bf16x8, aF[s][mi]), __builtin_bit_cast(bf16x8, BF[s][nj]), \
        acc[mq][nq][mi][nj], 0, 0, 0); \
  __builtin_amdgcn_s_setprio(0); \
} while (0)

  // prologue: stage buf0 <- ks=0 in consumption-aligned order A0,B0,B1,A1
  stageA(0, 0, 0); stageB(0, 0, 0); stageB(0, 1, 0); stageA(0, 1, 0);
  VM4; BAR;

  for (int it = 0; it < NIT - 1; ++it) {
    const int ks1 = 2 * it + 1, ks2 = 2 * it + 2;
    stageA(1, 0, ks1); LOAD_A(0, 0); LOAD_B(0, 0, bF0); VM4; BAR; MFMA_Q(0, 0, bF0);
    stageB(1, 0, ks1); LOAD_B(0, 1, bF1);               VM4; BAR; MFMA_Q(0, 1, bF1);
    stageB(1, 1, ks1); LOAD_A(0, 1);                         BAR; MFMA_Q(1, 1, bF1);
    stageA(1, 1, ks1);                                  VM4; BAR; MFMA_Q(1, 0, bF0);
    stageA(0, 0, ks2); LOAD_A(1, 0); LOAD_B(1, 0, bF0); VM4; BAR; MFMA_Q(0, 0, bF0);
    stageB(0, 0, ks2); LOAD_B(1, 1, bF1);               VM4; BAR; MFMA_Q(0, 1, bF1);
    stageB(0, 1, ks2); LOAD_A(1, 1);                         BAR; MFMA_Q(1, 1, bF1);
    stageA(0, 1, ks2);                                  VM4; BAR; MFMA_Q(1, 0, bF0);
  }
  {
    const int ks1 = 2 * (NIT - 1) + 1;
    stageA(1, 0, ks1); LOAD_A(0, 0); LOAD_B(0, 0, bF0); VM4; BAR; MFMA_Q(0, 0, bF0);
    stageB(1, 0, ks1); LOAD_B(0, 1, bF1);               VM4; BAR; MFMA_Q(0, 1, bF1);
    stageB(1, 1, ks1); LOAD_A(0, 1);                         BAR; MFMA_Q(1, 1, bF1);
    stageA(1, 1, ks1);                                  VM4; BAR; MFMA_Q(1, 0, bF0);
    LOAD_A(1, 0); LOAD_B(1, 0, bF0);                    VM2; BAR; MFMA_Q(0, 0, bF0);
    LOAD_B(1, 1, bF1);                                  VM0; BAR; MFMA_Q(0, 1, bF1);
    LOAD_A(1, 1);                                            BAR; MFMA_Q(1, 1, bF1);
                                                             BAR; MFMA_Q(1, 0, bF0);
  }

  // epilogue: D layout col=lane&15 (pixel), row=(lane>>4)*4+q (out-channel)
#pragma unroll
  for (int mq = 0; mq < 2; ++mq)
#pragma unroll
  for (int nq = 0; nq < 2; ++nq)
#pragma unroll
  for (int mi = 0; mi < 4; ++mi)
#pragma unroll
  for (int nj = 0; nj < 2; ++nj) {
    float* ob = out
      + ((size_t)(b * 512 + orow0 + (mq << 7) + (wm << 6) + (mi << 4) + (lk << 2)) << 12)
      + prow0 + (nq << 7) + (wn << 5) + (nj << 4) + lr;
#pragma unroll
    for (int q = 0; q < 4; ++q)
      ob[(size_t)q << 12] = acc[mq][nq][mi][nj][q];
  }
#undef VM4
#undef VM2
#undef VM0
#undef FENCE
#undef BAR
#undef LOAD_A
#undef LOAD_B
#undef MFMA_Q
}

extern "C" void kernel_launch(void* const* d_in, const int* in_sizes, int n_in,
                              void* d_out, int out_size, void* d_ws, size_t ws_size,
                              hipStream_t stream) {
  const float* fmap    = (const float*)d_in[0];
  const float* embed   = (const float*)d_in[1];
  const float* wbank   = (const float*)d_in[2];
  const float* mod_w   = (const float*)d_in[3];
  const float* mod_b   = (const float*)d_in[4];
  const float* adapt_w = (const float*)d_in[5];
  const float* adapt_b = (const float*)d_in[6];
  float* out = (float*)d_out;

  char* ws = (char*)d_ws;
  float* sel = (float*)ws;                                   // 128 B
  float* mod = (float*)(ws + 256);                           // 16 KB
  unsigned short* wts = (unsigned short*)(ws + 256 + 16384); // 37,748,736 B
  unsigned short* xt  = (unsigned short*)(ws + 256 + 16384 + (size_t)NB * DIMO * KTOT * 2);
  // xt: 8*66*72*512*2 = 38,928,384 B ; total ws use ~76.7 MB

  prep_embed<<<72, 256, 0, stream>>>(embed, mod_w, mod_b, adapt_w, adapt_b, mod, sel);
  prep_wf<<<1040, 256, 0, stream>>>(wbank, sel, mod, fmap, wts, xt);

  (void)hipFuncSetAttribute((const void*)conv_gemm,
                            hipFuncAttributeMaxDynamicSharedMemorySize, 131072);
  conv_gemm<<<dim3(256), dim3(512), 131072, stream>>>(wts, xt, out);
}

// Round 13
// 160.166 us; speedup vs baseline: 1.0389x; 1.0389x over previous
//
#include <hip/hip_runtime.h>
#include <stdint.h>

typedef short s16x8 __attribute__((ext_vector_type(8)));
typedef __bf16 bf16x8 __attribute__((ext_vector_type(8)));
typedef float f32x4 __attribute__((ext_vector_type(4)));

#define NB 8
#define DIM 512
#define DIMO 512
#define DEMB 512
#define NKER 4
#define HH 64
#define WW 64
#define HP 66
#define WP 72
#define KTOT 4608   // 9 * 512
#define NIT 36      // 72 K-steps of 64, 2 per iteration

__device__ __forceinline__ unsigned short f2bf(float f) {
  unsigned int u = __builtin_bit_cast(unsigned int, f);
  u += 0x7fffu + ((u >> 16) & 1u);
  return (unsigned short)(u >> 16);
}

// ------- kernel 1: fused prep: fmap transpose/pad/cast (blocks 0..527) +
//                   embed GEMVs mod/sel (blocks 528..599) ------- [round-11 best: 160.2us total]
__global__ void prep_all(const float* __restrict__ fmap,
                         const float* __restrict__ embed,
                         const float* __restrict__ mod_w,
                         const float* __restrict__ mod_b,
                         const float* __restrict__ adapt_w,
                         const float* __restrict__ adapt_b,
                         unsigned short* __restrict__ xt,
                         float* __restrict__ mod, float* __restrict__ sel) {
  const int bid = blockIdx.x;
  const int t = threadIdx.x;

  if (bid < 528) {   // ---- fmap part: b = bid/66, yp = bid%66 ----
    const int b = bid / 66;
    const int yp = bid - b * 66;
    unsigned short* rowb = xt + (((size_t)(b * HP + yp)) * WP) * DIM;
    uint4 z; z.x = 0; z.y = 0; z.z = 0; z.w = 0;

    if (yp == 0 || yp == HP - 1) {         // full-row zero: 72*512 shorts = 4608 uint4
      uint4* p = (uint4*)rowb;
#pragma unroll
      for (int r = 0; r < 18; ++r) p[t + r * 256] = z;
      return;
    }
    // x-halo zero: 8 px (0, 65..71) x 512 ch
#pragma unroll
    for (int r = 0; r < 2; ++r) {
      int idx = t + r * 256;               // 0..511
      int pxi = idx >> 6;                  // 0..7
      int px = pxi ? (64 + pxi) : 0;
      ((uint4*)(rowb + (size_t)px * DIM))[idx & 63] = z;
    }
    // interior transpose: y = yp-1, x = 0..63 -> px = x+1
    const int x = t & 63;
    const int ic0 = (t >> 6) * 8;
    const float* fb = fmap + (size_t)b * DIM * (HH * WW) + (size_t)(yp - 1) * WW + x;
    unsigned short* ob = rowb + (size_t)(x + 1) * DIM;
    for (int r = 0; r < 16; ++r) {
      int i0 = ic0 + r * 32;
      s16x8 vv;
#pragma unroll
      for (int j = 0; j < 8; ++j)
        vv[j] = (short)f2bf(fb[(size_t)(i0 + j) * (HH * WW)]);
      *(s16x8*)&ob[i0] = vv;
    }
    return;
  }

  // ---- embed part: e = bid-528; xchunk = e%9, b = e/9 ----
  const int e9 = bid - 528;
  const int b = e9 / 9;
  const int xc = e9 - b * 9;
  const int lane = t & 63, wv = t >> 6;
  const float* e = embed + (size_t)b * DEMB;

  if (xc == 8) {   // sel softmax: wave 0 only
    if (wv == 0) {
      float lg[NKER];
#pragma unroll
      for (int n = 0; n < NKER; ++n) {
        const float* ar = adapt_w + (size_t)n * DEMB;
        float s = 0.f;
#pragma unroll
        for (int k = 0; k < 8; ++k) s += e[lane + 64 * k] * ar[lane + 64 * k];
#pragma unroll
        for (int off = 32; off; off >>= 1) s += __shfl_xor(s, off);
        lg[n] = s + adapt_b[n];
      }
      if (lane == 0) {
        float m = lg[0];
#pragma unroll
        for (int n = 1; n < NKER; ++n) m = fmaxf(m, lg[n]);
        float ex[NKER], sum = 0.f;
#pragma unroll
        for (int n = 0; n < NKER; ++n) { ex[n] = expf(lg[n] - m); sum += ex[n]; }
#pragma unroll
        for (int n = 0; n < NKER; ++n) sel[b * NKER + n] = ex[n] / sum;
      }
    }
    return;
  }

  float ev[8];
#pragma unroll
  for (int k = 0; k < 8; ++k) ev[k] = e[lane + 64 * k];
  const int i0 = xc * 64 + wv * 16;
  for (int r = 0; r < 16; ++r) {
    const float* wr = mod_w + (size_t)(i0 + r) * DEMB;
    float s = 0.f;
#pragma unroll
    for (int k = 0; k < 8; ++k) s += ev[k] * wr[lane + 64 * k];
#pragma unroll
    for (int off = 32; off; off >>= 1) s += __shfl_xor(s, off);
    if (lane == 0) mod[b * DIM + i0 + r] = s + mod_b[i0 + r];
  }
}

// ------- kernel 2: per-o block; coalesced stage -> LDS once, hoist to regs, loop b -------
// out layout: wts[b][o][(ky*3+kx)*512+i] bf16
// Register hoist: thread's 72 b-invariant source values read from LDS ONCE; b-loop is
// pure VALU + coalesced writes. At the HBM floor (~75MB moved -> ~12us + overhead).
__global__ void prep_weights(const float* __restrict__ wbank,
                             const float* __restrict__ sel,
                             const float* __restrict__ mod,
                             unsigned short* __restrict__ wts) {
  const int o = blockIdx.x;          // 512 blocks
  const int t = threadIdx.x;         // 256 threads
  extern __shared__ float ls[];      // [4][4608] linear (i*9+kykx) order
  __shared__ float red[8];           // parity-alternating reduction slots

#pragma unroll
  for (int n = 0; n < NKER; ++n) {
    const float* wb = wbank + ((size_t)n * DIMO + o) * (DIM * 9);
#pragma unroll
    for (int r = 0; r < 18; ++r) {
      int ii = t + r * 256;
      ls[n * KTOT + ii] = wb[ii];    // coalesced global read, linear LDS write
    }
  }
  __syncthreads();

  // hoist: output slot ok = t + r*256 = kykx*512 + i with kykx = r>>1, i = t + (r&1)*256
  // -> src = i*9 + kykx = (t + p*256)*9 + g ; wreg[n][p][g], 72 VGPRs, b-invariant.
  // LDS bank: stride-9, 9 coprime 32 -> 2-way conflict (free).
  float wreg[NKER][2][9];
#pragma unroll
  for (int n = 0; n < NKER; ++n)
#pragma unroll
    for (int p = 0; p < 2; ++p)
#pragma unroll
      for (int g = 0; g < 9; ++g)
        wreg[n][p][g] = ls[n * KTOT + (t + p * 256) * 9 + g];

  const int lane = t & 63, wv = t >> 6;
  for (int b = 0; b < NB; ++b) {
    const float s0 = sel[b * NKER + 0], s1 = sel[b * NKER + 1];
    const float s2 = sel[b * NKER + 2], s3 = sel[b * NKER + 3];
    const float m0 = mod[b * DIM + t] + 1.0f;
    const float m1 = mod[b * DIM + t + 256] + 1.0f;
    const int par = (b & 1) << 2;

    float vv[18];
    float ss = 0.f;
#pragma unroll
    for (int r = 0; r < 18; ++r) {
      const int p = r & 1, g = r >> 1;
      float w = s0 * wreg[0][p][g] + s1 * wreg[1][p][g]
              + s2 * wreg[2][p][g] + s3 * wreg[3][p][g];
      w *= (p ? m1 : m0);
      vv[r] = w;
      ss += w * w;
    }
    for (int off = 32; off > 0; off >>= 1) ss += __shfl_down(ss, off);
    if (lane == 0) red[wv + par] = ss;
    __syncthreads();
    float tot = red[0 + par] + red[1 + par] + red[2 + par] + red[3 + par];
    float inv = rsqrtf(fmaxf(tot, 1e-8f));
    unsigned short* wo = wts + ((size_t)(b * DIMO + o)) * KTOT;
#pragma unroll
    for (int r = 0; r < 18; ++r)
      wo[t + r * 256] = f2bf(vv[r] * inv);
    // no trailing sync: next b writes the other red[] parity
  }
}

// ---------------- kernel 3: implicit-GEMM conv, 256x256 tile, 8-phase schedule ----------------
// Per batch: C[512 o][4096 p] = A[512][4608] . B[4096][4608]^T (both K-contiguous).
// BM=BN=256, BK=64, 8 waves (2M x 4N), per-wave 128x64. LDS 128KB: 2 dbuf x (A 32KB + B 32KB).
// XCD-chunked block swizzle: XCD i owns batch i. Proven schedule (123.3us, MfmaUtil 55%,
// 0 bank conflicts). Refuted alternatives: 32x32 MFMA (bank conflicts + dep chains, +31us),
// NT stores (WRITE +28%, +7us).
__global__ __launch_bounds__(512, 2) void conv_gemm(
    const unsigned short* __restrict__ wts,  // [8][512][4608] bf16
    const unsigned short* __restrict__ xt,   // [8][66][72][512] bf16
    float* __restrict__ out) {               // [8][512][64][64] f32
  extern __shared__ __attribute__((aligned(16))) char smem[];

  const int tid = threadIdx.x;
  const int w = tid >> 6, l = tid & 63;
  const int bid0 = blockIdx.x;
  const int bid = ((bid0 & 7) << 5) | (bid0 >> 3);   // T1: 8 XCDs x 32 blocks, bijective
  const int b = bid >> 5;
  const int mt = (bid >> 4) & 1;
  const int nt = bid & 15;
  const int orow0 = mt << 8;
  const int prow0 = nt << 8;
  const int y0 = nt << 2;                  // 4 image rows per 256-pixel tile
  const int wm = w >> 2, wn = w & 3;       // 2 x 4 wave grid
  const int lr = l & 15, lk = l >> 4;

  const unsigned short* a_base = wts + (size_t)(b * 512 + orow0) * KTOT;
  const unsigned short* x_base = xt + (size_t)b * (HP * WP * DIM);

  const int srow = (w << 3) + (l >> 3);                 // row within 64-row issue
  const int sx8 = (((l & 7) ^ ((l >> 3) & 7)) << 3);    // source chunk (elements), involution
  const int sw0 = ((lk ^ (l & 7)) << 4);                // frag-read byte offset, s=0 (s=1: ^64)
  const int aRow = (((wm << 6) + lr) << 7);
  const int bRow = (((wn << 5) + lr) << 7);

  // per-lane iteration-invariant pixel bases for stageB: (h,j) in {0,1}^2
  int pb[2][2];
#pragma unroll
  for (int h = 0; h < 2; ++h)
#pragma unroll
    for (int j = 0; j < 2; ++j) {
      const int pl = (h << 7) + (j << 6) + srow;
      pb[h][j] = (((y0 + (pl >> 6)) * WP + (pl & 63)) << 9);
    }

  f32x4 acc[2][2][4][2] = {};
  s16x8 aF[2][4], bF0[2][2], bF1[2][2];

  auto stageA = [&](int d, int h, int ks) {
#pragma unroll
    for (int j = 0; j < 2; ++j) {
      const unsigned short* gp = a_base + (size_t)((h << 7) + (j << 6) + srow) * KTOT
                               + (ks << 6) + sx8;
      __builtin_amdgcn_global_load_lds(
          (const __attribute__((address_space(1))) void*)gp,
          (__attribute__((address_space(3))) void*)(smem + (d << 16) + (h << 14) + (j << 13) + (w << 10)),
          16, 0, 0);
    }
  };
  auto stageB = [&](int d, int h, int ks) {
    // uniform k-offset: kykx = ks>>3, ky = kykx/3 via (t*11)>>5 (exact for t in 0..8)
    const int t9 = ks >> 3;
    const int ky = (t9 * 11) >> 5;
    const int koff = ky * (WP << 9) + (t9 - 3 * ky) * 512 + ((ks & 7) << 6);
#pragma unroll
    for (int j = 0; j < 2; ++j) {
      const unsigned short* gp = x_base + pb[h][j] + koff + sx8;
      __builtin_amdgcn_global_load_lds(
          (const __attribute__((address_space(1))) void*)gp,
          (__attribute__((address_space(3))) void*)(smem + (d << 16) + 32768 + (h << 14) + (j << 13) + (w << 10)),
          16, 0, 0);
    }
  };

#define VM4 asm volatile("s_waitcnt vmcnt(4)" ::: "memory")
#define VM2 asm volatile("s_waitcnt vmcnt(2)" ::: "memory")
#define VM0 asm volatile("s_waitcnt vmcnt(0)" ::: "memory")
#define FENCE asm volatile("" ::: "memory")
#define BAR do { FENCE; __builtin_amdgcn_s_barrier(); FENCE; } while (0)

#define LOAD_A(d, mq) \
  _Pragma("unroll") for (int s = 0; s < 2; ++s) \
  _Pragma("unroll") for (int mi = 0; mi < 4; ++mi) \
    aF[s][mi] = *(const s16x8*)(smem + ((d) << 16) + ((mq) << 14) + aRow + (mi << 11) + (sw0 ^ (s << 6)));

#define LOAD_B(d, nq, BF) \
  _Pragma("unroll") for (int s = 0; s < 2; ++s) \
  _Pragma("unroll") for (int nj = 0; nj < 2; ++nj) \
    BF[s][nj] = *(const s16x8*)(smem + ((d) << 16) + 32768 + ((nq) << 14) + bRow + (nj << 11) + (sw0 ^ (s << 6)));

#define MFMA_Q(mq, nq, BF) do { \
  __builtin_amdgcn_s_setprio(1); \
  _Pragma("unroll") for (int s = 0; s < 2; ++s) \
  _Pragma("unroll") for (int mi = 0; mi < 4; ++mi) \
  _Pragma("unroll") for (int nj = 0; nj < 2; ++nj) \
    acc[mq][nq][mi][nj] = __builtin_amdgcn_mfma_f32_16x16x32_bf16( \
        __builtin_bit_cast(bf16x8, aF[s][mi]), __builtin_bit_cast(bf16x8, BF[s][nj]), \
        acc[mq][nq][mi][nj], 0, 0, 0); \
  __builtin_amdgcn_s_setprio(0); \
} while (0)

  // prologue: stage buf0 <- ks=0 in consumption-aligned order A0,B0,B1,A1
  stageA(0, 0, 0); stageB(0, 0, 0); stageB(0, 1, 0); stageA(0, 1, 0);
  VM4; BAR;

  for (int it = 0; it < NIT - 1; ++it) {
    const int ks1 = 2 * it + 1, ks2 = 2 * it + 2;
    stageA(1, 0, ks1); LOAD_A(0, 0); LOAD_B(0, 0, bF0); VM4; BAR; MFMA_Q(0, 0, bF0);
    stageB(1, 0, ks1); LOAD_B(0, 1, bF1);               VM4; BAR; MFMA_Q(0, 1, bF1);
    stageB(1, 1, ks1); LOAD_A(0, 1);                         BAR; MFMA_Q(1, 1, bF1);
    stageA(1, 1, ks1);                                  VM4; BAR; MFMA_Q(1, 0, bF0);
    stageA(0, 0, ks2); LOAD_A(1, 0); LOAD_B(1, 0, bF0); VM4; BAR; MFMA_Q(0, 0, bF0);
    stageB(0, 0, ks2); LOAD_B(1, 1, bF1);               VM4; BAR; MFMA_Q(0, 1, bF1);
    stageB(0, 1, ks2); LOAD_A(1, 1);                         BAR; MFMA_Q(1, 1, bF1);
    stageA(0, 1, ks2);                                  VM4; BAR; MFMA_Q(1, 0, bF0);
  }
  {
    const int ks1 = 2 * (NIT - 1) + 1;
    stageA(1, 0, ks1); LOAD_A(0, 0); LOAD_B(0, 0, bF0); VM4; BAR; MFMA_Q(0, 0, bF0);
    stageB(1, 0, ks1); LOAD_B(0, 1, bF1);               VM4; BAR; MFMA_Q(0, 1, bF1);
    stageB(1, 1, ks1); LOAD_A(0, 1);                         BAR; MFMA_Q(1, 1, bF1);
    stageA(1, 1, ks1);                                  VM4; BAR; MFMA_Q(1, 0, bF0);
    LOAD_A(1, 0); LOAD_B(1, 0, bF0);                    VM2; BAR; MFMA_Q(0, 0, bF0);
    LOAD_B(1, 1, bF1);                                  VM0; BAR; MFMA_Q(0, 1, bF1);
    LOAD_A(1, 1);                                            BAR; MFMA_Q(1, 1, bF1);
                                                             BAR; MFMA_Q(1, 0, bF0);
  }

  // epilogue: D layout col=lane&15 (pixel), row=(lane>>4)*4+q (out-channel)
#pragma unroll
  for (int mq = 0; mq < 2; ++mq)
#pragma unroll
  for (int nq = 0; nq < 2; ++nq)
#pragma unroll
  for (int mi = 0; mi < 4; ++mi)
#pragma unroll
  for (int nj = 0; nj < 2; ++nj) {
    float* ob = out
      + ((size_t)(b * 512 + orow0 + (mq << 7) + (wm << 6) + (mi << 4) + (lk << 2)) << 12)
      + prow0 + (nq << 7) + (wn << 5) + (nj << 4) + lr;
#pragma unroll
    for (int q = 0; q < 4; ++q)
      ob[(size_t)q << 12] = acc[mq][nq][mi][nj][q];
  }
#undef VM4
#undef VM2
#undef VM0
#undef FENCE
#undef BAR
#undef LOAD_A
#undef LOAD_B
#undef MFMA_Q
}

extern "C" void kernel_launch(void* const* d_in, const int* in_sizes, int n_in,
                              void* d_out, int out_size, void* d_ws, size_t ws_size,
                              hipStream_t stream) {
  const float* fmap    = (const float*)d_in[0];
  const float* embed   = (const float*)d_in[1];
  const float* wbank   = (const float*)d_in[2];
  const float* mod_w   = (const float*)d_in[3];
  const float* mod_b   = (const float*)d_in[4];
  const float* adapt_w = (const float*)d_in[5];
  const float* adapt_b = (const float*)d_in[6];
  float* out = (float*)d_out;

  char* ws = (char*)d_ws;
  float* sel = (float*)ws;                                   // 128 B
  float* mod = (float*)(ws + 256);                           // 16 KB
  unsigned short* wts = (unsigned short*)(ws + 256 + 16384); // 37,748,736 B
  unsigned short* xt  = (unsigned short*)(ws + 256 + 16384 + (size_t)NB * DIMO * KTOT * 2);
  // xt: 8*66*72*512*2 = 38,928,384 B ; total ws use ~76.7 MB

  prep_all<<<600, 256, 0, stream>>>(fmap, embed, mod_w, mod_b, adapt_w, adapt_b,
                                    xt, mod, sel);

  (void)hipFuncSetAttribute((const void*)prep_weights,
                            hipFuncAttributeMaxDynamicSharedMemorySize, 73728);
  prep_weights<<<512, 256, 73728, stream>>>(wbank, sel, mod, wts);

  (void)hipFuncSetAttribute((const void*)conv_gemm,
                            hipFuncAttributeMaxDynamicSharedMemorySize, 131072);
  conv_gemm<<<dim3(256), dim3(512), 131072, stream>>>(wts, xt, out);
}